// Round 9
// baseline (285.567 us; speedup 1.0000x reference)
//
#include <hip/hip_runtime.h>
#include <math.h>

typedef unsigned short u16;
typedef __attribute__((ext_vector_type(8))) short v8bf;
typedef __attribute__((ext_vector_type(4))) float f32x4;

#define N_TOK 4096
#define DMODEL 512
#define NHEAD 8
#define HDIM 64
#define CANDN 64
#define NBINS 512
#define BINCAP 64
#define QCAP 128
#define ATT_SCALE 0.125f
#define MAX_NORM_F 0.99999f

__device__ __forceinline__ float bf2f(u16 u) {
  union { unsigned int i; float f; } v; v.i = ((unsigned int)u) << 16; return v.f;
}
__device__ __forceinline__ u16 f2bf(float f) {
  union { float f; unsigned int i; } v; v.f = f;
  unsigned int x = v.i;
  return (u16)((x + 0x7fffu + ((x >> 16) & 1u)) >> 16);
}
__device__ __forceinline__ uint4 load_pack8(const float* __restrict__ p) {
  const float4 x0 = *(const float4*)p;
  const float4 x1 = *(const float4*)(p + 4);
  union { u16 h[8]; uint4 u; } r;
  r.h[0] = f2bf(x0.x); r.h[1] = f2bf(x0.y); r.h[2] = f2bf(x0.z); r.h[3] = f2bf(x0.w);
  r.h[4] = f2bf(x1.x); r.h[5] = f2bf(x1.y); r.h[6] = f2bf(x1.z); r.h[7] = f2bf(x1.w);
  return r.u;
}

// ---------------------------------------------------------------------------
// prep: blocks 0..511 = bins pass 1 (f64 dots + boundary flags, byte array
// fully written each call -> no init dispatch). Blocks 512..4095 = one-shot
// f32->bf16 RNE convert of query/key/value/Wq/Wk/Wv/Wo (same RNE point as
// R8's in-GEMM load_pack8 -> bit-identical numerics).
// ---------------------------------------------------------------------------
__global__ __launch_bounds__(256) void prep_kernel(
    const float* __restrict__ query, const float* __restrict__ key_,
    const float* __restrict__ value,
    const float* __restrict__ Wq, const float* __restrict__ Wk,
    const float* __restrict__ Wv, const float* __restrict__ Wo,
    u16* __restrict__ qx, u16* __restrict__ kx, u16* __restrict__ vx,
    u16* __restrict__ wqx, u16* __restrict__ wkx, u16* __restrict__ wvx,
    u16* __restrict__ wox,
    int* __restrict__ qb, int* __restrict__ kb, unsigned char* __restrict__ flags)
{
  __shared__ float xs[16 * 516];
  const int blk = blockIdx.x;
  const int tid = threadIdx.x;

  if (blk >= 512) {  // convert path
    const int rel = blk - 512;
    const float* src; u16* dst; int base;
    if (rel < 1024)      { src = query; dst = qx; base = rel << 11; }
    else if (rel < 2048) { src = key_;  dst = kx; base = (rel - 1024) << 11; }
    else if (rel < 3072) { src = value; dst = vx; base = (rel - 2048) << 11; }
    else {
      const int r2 = rel - 3072; const int w = r2 >> 7;
      src = (w == 0) ? Wq : (w == 1) ? Wk : (w == 2) ? Wv : Wo;
      dst = (w == 0) ? wqx : (w == 1) ? wkx : (w == 2) ? wvx : wox;
      base = (r2 & 127) << 11;
    }
    const int off = base + tid * 8;
    *(uint4*)(dst + off) = load_pack8(src + off);
    return;
  }

  // bins pass 1 (R8-verified): 16-row LDS tile, 16 threads share a row
  const int isk  = blk >> 8;
  const int tile = blk & 255;
  const float* X = isk ? key_ : query;
  const float* W = isk ? Wk : Wq;

#pragma unroll
  for (int i = 0; i < 8; ++i) {
    const int flat = i * 1024 + tid * 4;
    const int row = flat >> 9, col = flat & 511;
    *(float4*)&xs[row * 516 + col] = *(const float4*)(X + (tile * 16 + row) * DMODEL + col);
  }
  __syncthreads();

  const int n_local = tid >> 4;
  const int pair = tid & 15;
  const int h = pair >> 1, coord = pair & 1;
  const float* wrow = W + ((h << 6) + coord) * DMODEL;
  const float* xrow = &xs[n_local * 516];

  double c0 = 0.0, c1 = 0.0, c2 = 0.0, c3 = 0.0;
  for (int k = 0; k < DMODEL; k += 4) {
    const float4 xv = *(const float4*)(xrow + k);
    const float4 wv = *(const float4*)(wrow + k);
    c0 = fma((double)xv.x, (double)wv.x, c0);
    c1 = fma((double)xv.y, (double)wv.y, c1);
    c2 = fma((double)xv.z, (double)wv.z, c2);
    c3 = fma((double)xv.w, (double)wv.w, c3);
  }
  const double a = (c0 + c1) + (c2 + c3);
  const double other = __shfl_xor(a, 1);
  if (coord == 0) {
    const double a0 = a, a1 = other;
    const int n = tile * 16 + n_local;
    double ang = atan2(a1, a0);
    double t = (ang / 6.283185307179586 + 0.5) * 512.0;
    int b = (int)floor(t);
    b = b < 0 ? 0 : (b > 511 ? 511 : b);
    (isk ? kb : qb)[(h << 12) + n] = b;

    const double r = sqrt(a0 * a0 + a1 * a1);
    const double dist = fabs(t - nearbyint(t));
    const double margin = fmin(0.45, 3.3e-4 / fmax(r, 1e-30) + 5e-5);
    flags[(isk << 15) | (h << 12) | n] = (dist < margin) ? 1 : 0;
  }
}

// ---------------------------------------------------------------------------
// GEMM 128x128 tile, BK=32 — pure bf16 operands (preconverted), zero staging
// VALU. Poincare projection fused into Q/K epilogue; Q/K/V stored bf16.
// ---------------------------------------------------------------------------
__global__ __launch_bounds__(256) void gemm_qkv_kernel(
    const u16* __restrict__ qx, const u16* __restrict__ kx, const u16* __restrict__ vx,
    const u16* __restrict__ wqx, const u16* __restrict__ wkx, const u16* __restrict__ wvx,
    const float* __restrict__ bq, const float* __restrict__ bk, const float* __restrict__ bv,
    u16* __restrict__ Qb, u16* __restrict__ Kb, u16* __restrict__ Vb)
{
  const int z = blockIdx.z;
  const u16* A    = (z == 0) ? qx : (z == 1) ? kx : vx;
  const u16* W    = (z == 0) ? wqx : (z == 1) ? wkx : wvx;
  const float* bias = (z == 0) ? bq : (z == 1) ? bk : bv;
  u16* O          = (z == 0) ? Qb : (z == 1) ? Kb : Vb;

  __shared__ u16 As[128 * 40];
  __shared__ u16 Ws[128 * 40];

  const int tid  = threadIdx.x;
  const int lane = tid & 63;
  const int wave = tid >> 6;
  const int row4 = tid >> 2;
  const int seg  = tid & 3;

  const int bm = blockIdx.x * 128;
  const int bn = blockIdx.y * 128;
  const int wm = (wave & 1) * 64;
  const int wn = (wave >> 1) * 64;
  const int l15 = lane & 15;
  const int quad = lane >> 4;

  f32x4 acc[4][4] = {};

  for (int kt = 0; kt < DMODEL; kt += 32) {
    uint4 a0 = *(const uint4*)(A + (bm + row4) * DMODEL + kt + seg * 8);
    uint4 a1 = *(const uint4*)(A + (bm + row4 + 64) * DMODEL + kt + seg * 8);
    uint4 w0 = *(const uint4*)(W + (bn + row4) * DMODEL + kt + seg * 8);
    uint4 w1 = *(const uint4*)(W + (bn + row4 + 64) * DMODEL + kt + seg * 8);
    __syncthreads();
    *(uint4*)&As[row4 * 40 + seg * 8] = a0;
    *(uint4*)&As[(row4 + 64) * 40 + seg * 8] = a1;
    *(uint4*)&Ws[row4 * 40 + seg * 8] = w0;
    *(uint4*)&Ws[(row4 + 64) * 40 + seg * 8] = w1;
    __syncthreads();
    v8bf af[4], bfr[4];
#pragma unroll
    for (int i = 0; i < 4; ++i)
      af[i] = *(const v8bf*)&As[(wm + i * 16 + l15) * 40 + quad * 8];
#pragma unroll
    for (int j = 0; j < 4; ++j)
      bfr[j] = *(const v8bf*)&Ws[(wn + j * 16 + l15) * 40 + quad * 8];
#pragma unroll
    for (int i = 0; i < 4; ++i)
#pragma unroll
      for (int j = 0; j < 4; ++j)
        acc[i][j] = __builtin_amdgcn_mfma_f32_16x16x32_bf16(af[i], bfr[j], acc[i][j], 0, 0, 0);
  }

  float bval[4];
#pragma unroll
  for (int j = 0; j < 4; ++j) bval[j] = bias[bn + wn + j * 16 + l15];
  const int h = (bn + wn) >> 6;

#pragma unroll
  for (int i = 0; i < 4; ++i) {
#pragma unroll
    for (int r = 0; r < 4; ++r) {
      const int row = bm + wm + i * 16 + quad * 4 + r;
      float v0 = acc[i][0][r] + bval[0];
      float v1 = acc[i][1][r] + bval[1];
      float v2 = acc[i][2][r] + bval[2];
      float v3 = acc[i][3][r] + bval[3];
      if (z != 2) {
        float ss = v0 * v0 + v1 * v1 + v2 * v2 + v3 * v3;
#pragma unroll
        for (int o = 1; o < 16; o <<= 1) ss += __shfl_xor(ss, o);
        const float s = fminf(1.0f, MAX_NORM_F / fmaxf(sqrtf(ss), 1e-12f));
        v0 *= s; v1 *= s; v2 *= s; v3 *= s;
      }
      const int base = (((h << 12) + row) << 6) + l15;
      O[base +  0] = f2bf(v0); O[base + 16] = f2bf(v1);
      O[base + 32] = f2bf(v2); O[base + 48] = f2bf(v3);
    }
  }
}

__global__ __launch_bounds__(256) void gemm_out_kernel(
    const u16* __restrict__ A, const u16* __restrict__ W,
    const float* __restrict__ bias, float* __restrict__ O)
{
  __shared__ u16 As[128 * 40];
  __shared__ u16 Ws[128 * 40];

  const int tid  = threadIdx.x;
  const int lane = tid & 63;
  const int wave = tid >> 6;
  const int row4 = tid >> 2;
  const int seg  = tid & 3;

  const int bm = blockIdx.x * 128;
  const int bn = blockIdx.y * 128;
  const int wm = (wave & 1) * 64;
  const int wn = (wave >> 1) * 64;
  const int l15 = lane & 15;
  const int quad = lane >> 4;

  f32x4 acc[4][4] = {};

  for (int kt = 0; kt < DMODEL; kt += 32) {
    uint4 a0 = *(const uint4*)(A + (bm + row4) * DMODEL + kt + seg * 8);
    uint4 a1 = *(const uint4*)(A + (bm + row4 + 64) * DMODEL + kt + seg * 8);
    uint4 w0 = *(const uint4*)(W + (bn + row4) * DMODEL + kt + seg * 8);
    uint4 w1 = *(const uint4*)(W + (bn + row4 + 64) * DMODEL + kt + seg * 8);
    __syncthreads();
    *(uint4*)&As[row4 * 40 + seg * 8] = a0;
    *(uint4*)&As[(row4 + 64) * 40 + seg * 8] = a1;
    *(uint4*)&Ws[row4 * 40 + seg * 8] = w0;
    *(uint4*)&Ws[(row4 + 64) * 40 + seg * 8] = w1;
    __syncthreads();
    v8bf af[4], bfr[4];
#pragma unroll
    for (int i = 0; i < 4; ++i)
      af[i] = *(const v8bf*)&As[(wm + i * 16 + l15) * 40 + quad * 8];
#pragma unroll
    for (int j = 0; j < 4; ++j)
      bfr[j] = *(const v8bf*)&Ws[(wn + j * 16 + l15) * 40 + quad * 8];
#pragma unroll
    for (int i = 0; i < 4; ++i)
#pragma unroll
      for (int j = 0; j < 4; ++j)
        acc[i][j] = __builtin_amdgcn_mfma_f32_16x16x32_bf16(af[i], bfr[j], acc[i][j], 0, 0, 0);
  }

#pragma unroll
  for (int j = 0; j < 4; ++j) {
    const int cg = bn + wn + j * 16 + l15;
    const float bval = bias[cg];
#pragma unroll
    for (int i = 0; i < 4; ++i) {
      const int rbase = bm + wm + i * 16 + quad * 4;
#pragma unroll
      for (int r = 0; r < 4; ++r)
        O[(rbase + r) * DMODEL + cg] = acc[i][j][r] + bval;
    }
  }
}

// ---------------------------------------------------------------------------
// fdlibm atanf/atan2f ports (R5-verified, unchanged).
// ---------------------------------------------------------------------------
__device__ float fdlibm_atanf(float x) {
#pragma clang fp contract(off)
  const float atanhi[4] = {4.6364760399e-01f, 7.8539812565e-01f,
                           9.8279368877e-01f, 1.5707962513e+00f};
  const float atanlo[4] = {5.0121582440e-09f, 3.7748947079e-08f,
                           3.4473217170e-08f, 7.5497894159e-08f};
  const float aT[5] = {3.3333328366e-01f, -1.9999158382e-01f, 1.4253635705e-01f,
                       -1.0648017377e-01f, 6.1687607318e-02f};
  unsigned ix = __float_as_uint(x);
  const unsigned sign = ix >> 31;
  ix &= 0x7fffffffu;
  int id;
  float z, w, s1, s2;
  if (ix >= 0x4c800000u) {
    z = atanhi[3] + 0x1p-120f;
    return sign ? -z : z;
  }
  if (ix < 0x3ee00000u) {
    if (ix < 0x39800000u) return x;
    id = -1;
  } else {
    x = fabsf(x);
    if (ix < 0x3f980000u) {
      if (ix < 0x3f300000u) { id = 0; x = (2.0f * x - 1.0f) / (2.0f + x); }
      else                  { id = 1; x = (x - 1.0f) / (x + 1.0f); }
    } else {
      if (ix < 0x401c0000u) { id = 2; x = (x - 1.5f) / (1.0f + 1.5f * x); }
      else                  { id = 3; x = -1.0f / x; }
    }
  }
  z = x * x;
  w = z * z;
  s1 = z * (aT[0] + w * (aT[2] + w * aT[4]));
  s2 = w * (aT[1] + w * aT[3]);
  if (id < 0) return x - x * (s1 + s2);
  z = atanhi[id] - ((x * (s1 + s2) - atanlo[id]) - x);
  return sign ? -z : z;
}

__device__ float fdlibm_atan2f(float y, float x) {
#pragma clang fp contract(off)
  const float pi = 3.1415927410e+00f, pi_lo = -8.7422776573e-08f;
  const unsigned hx = __float_as_uint(x), hy = __float_as_uint(y);
  if (hx == 0x3f800000u) return fdlibm_atanf(y);
  const unsigned m = ((hy >> 31) & 1u) | ((hx >> 30) & 2u);
  const unsigned ix = hx & 0x7fffffffu, iy = hy & 0x7fffffffu;
  if (iy == 0u) {
    switch (m) { case 0: case 1: return y; case 2: return pi; default: return -pi; }
  }
  if (ix == 0u) return (m & 1u) ? -1.57079637050628662f : 1.57079637050628662f;
  float z;
  if (ix + (26u << 23) < iy) {
    z = 1.57079637050628662f;
    return (m & 1u) ? -z : z;
  }
  if ((m & 2u) && iy + (26u << 23) < ix) z = 0.0f;
  else z = fdlibm_atanf(fabsf(y / x));
  switch (m) {
    case 0: return z;
    case 1: return -z;
    case 2: return pi - (z - pi_lo);
    default: return (z - pi_lo) - pi;
  }
}

// ---------------------------------------------------------------------------
// combo: per (head, half-of-bins) block. Phase A: np-f32 bit-mimic fix of
// flagged bins (LDS-local). Phase B: key hist/append for bins [lo-1,lo+256]
// + per-slot insertion sort. Phase C: 3-way merge -> candb/ccntb. Phase D:
// query hist -> qhist/qlist. Replaces 4 dispatches of R8. LDS ~52 KB.
// ---------------------------------------------------------------------------
__global__ __launch_bounds__(256) void combo_kernel(
    const float* __restrict__ query, const float* __restrict__ key_,
    const float* __restrict__ Wq, const float* __restrict__ Wk,
    const int* __restrict__ qb, const int* __restrict__ kb,
    const unsigned char* __restrict__ flags,
    int* __restrict__ qhist, u16* __restrict__ qlist,
    int* __restrict__ ccntb, u16* __restrict__ candb)
{
  __shared__ short kbs[N_TOK];
  __shared__ short qbs[N_TOK];
  __shared__ int   wlc;
  __shared__ int   wle[128];
  __shared__ int   khist[258];
  __shared__ u16   klist[258 * 64];
  __shared__ int   qh[256];

  const int h = blockIdx.x >> 1;
  const int half = blockIdx.x & 1;
  const int lo = half << 8;
  const int tid = threadIdx.x;

  if (tid == 0) wlc = 0;
  for (int i = tid; i < N_TOK; i += 256) {
    kbs[i] = (short)kb[(h << 12) + i];
    qbs[i] = (short)qb[(h << 12) + i];
  }
  __syncthreads();

  // Phase A: collect flagged elements of this head
  for (int i = tid; i < 8192; i += 256) {
    const int isk = i >> 12, n = i & 4095;
    if (flags[(isk << 15) | (h << 12) | n]) {
      const int p = atomicAdd(&wlc, 1);
      if (p < 128) wle[p] = (isk << 12) | n;
    }
  }
  __syncthreads();
  int nw = wlc; if (nw > 128) nw = 128;
  const int wv = tid >> 6, ln = tid & 63;
  for (int e = wv; e < nw; e += 4) {
    const int code = wle[e];
    const int n = code & 4095;
    const int isk = code >> 12;
    const float* xr = (isk ? key_ : query) + n * DMODEL;
    const float* wr = (isk ? Wk : Wq) + ((h << 6) + ln) * DMODEL;
    float acc = 0.0f;
    for (int k = 0; k < DMODEL; k += 16) {
      const float4 xa = *(const float4*)(xr + k);
      const float4 xb = *(const float4*)(xr + k + 4);
      const float4 xc = *(const float4*)(xr + k + 8);
      const float4 xd = *(const float4*)(xr + k + 12);
      const float4 wa = *(const float4*)(wr + k);
      const float4 wb = *(const float4*)(wr + k + 4);
      const float4 wc = *(const float4*)(wr + k + 8);
      const float4 wd = *(const float4*)(wr + k + 12);
      acc = __fmaf_rn(xa.x, wa.x, acc); acc = __fmaf_rn(xa.y, wa.y, acc);
      acc = __fmaf_rn(xa.z, wa.z, acc); acc = __fmaf_rn(xa.w, wa.w, acc);
      acc = __fmaf_rn(xb.x, wb.x, acc); acc = __fmaf_rn(xb.y, wb.y, acc);
      acc = __fmaf_rn(xb.z, wb.z, acc); acc = __fmaf_rn(xb.w, wb.w, acc);
      acc = __fmaf_rn(xc.x, wc.x, acc); acc = __fmaf_rn(xc.y, wc.y, acc);
      acc = __fmaf_rn(xc.z, wc.z, acc); acc = __fmaf_rn(xc.w, wc.w, acc);
      acc = __fmaf_rn(xd.x, wd.x, acc); acc = __fmaf_rn(xd.y, wd.y, acc);
      acc = __fmaf_rn(xd.z, wd.z, acc); acc = __fmaf_rn(xd.w, wd.w, acc);
    }
    {
#pragma clang fp contract(off)
      const float sq = acc * acc;
      float rr[8];
#pragma unroll
      for (int j = 0; j < 8; ++j) rr[j] = __shfl(sq, j);
      for (int i = 8; i < 64; i += 8) {
#pragma unroll
        for (int j = 0; j < 8; ++j) rr[j] += __shfl(sq, i + j);
      }
      const float ss = ((rr[0] + rr[1]) + (rr[2] + rr[3])) +
                       ((rr[4] + rr[5]) + (rr[6] + rr[7]));
      const float nrm = __fsqrt_rn(ss);
      const float s = fminf(1.0f, 0.99999f / fmaxf(nrm, 1e-12f));
      const float c0 = __shfl(acc, 0) * s;
      const float c1 = __shfl(acc, 1) * s;
      const float cr = (float)atan2((double)c1, (double)c0);
      const float fd = fdlibm_atan2f(c1, c0);
      const float tol = fmaxf(fabsf(cr) * 6e-7f, 1e-30f);
      const float ang = (fabsf(fd - cr) <= tol) ? fd : cr;
      const float t = ((ang / 6.2831854820251465f) + 0.5f) * 512.0f;
      int b = (int)floorf(t);
      b = b < 0 ? 0 : (b > 511 ? 511 : b);
      if (ln == 0) (isk ? kbs : qbs)[n] = (short)b;
    }
  }
  __syncthreads();

  // Phase B: key hist+append (slot = bin - (lo-1), range [0,258))
  for (int i = tid; i < 258; i += 256) khist[i] = 0;
  for (int i = tid; i < 256; i += 256) qh[i] = 0;
  __syncthreads();
  for (int i = tid; i < N_TOK; i += 256) {
    const int sl = (int)kbs[i] - (lo - 1);
    if (sl >= 0 && sl < 258) {
      const int p = atomicAdd(&khist[sl], 1);
      if (p < BINCAP) klist[sl * 64 + p] = (u16)i;
    }
  }
  __syncthreads();
  for (int sl = tid; sl < 258; sl += 256) {
    int c = khist[sl];
    if (c > BINCAP) { c = BINCAP; khist[sl] = BINCAP; }
    u16* a = &klist[sl * 64];
    for (int i = 1; i < c; ++i) {
      const u16 kk = a[i];
      int j = i - 1;
      while (j >= 0 && a[j] > kk) { a[j + 1] = a[j]; --j; }
      a[j + 1] = kk;
    }
  }
  __syncthreads();

  // Phase C: merge per bin (thread tid <-> bin lo+tid)
  {
    const int b = lo + tid;
    const u16* L[3]; int C[3]; int nl = 0;
#pragma unroll
    for (int dl = 0; dl < 3; ++dl) {
      const int bin = b - 1 + dl;
      if (bin >= 0 && bin < NBINS) {
        const int c = khist[tid + dl];
        if (c > 0) { L[nl] = &klist[(tid + dl) * 64]; C[nl] = c; ++nl; }
      }
    }
    int p[3] = {0, 0, 0};
    int v[3];
#pragma unroll
    for (int l = 0; l < 3; ++l) v[l] = (l < nl) ? (int)L[l][0] : 0x10000;
    int r = 0;
    const int obase = ((h << 9) + b) << 6;
    while (r < CANDN) {
      int best = 0;
      if (v[1] < v[best]) best = 1;
      if (v[2] < v[best]) best = 2;
      const int mv = v[best];
      if (mv == 0x10000) break;
      candb[obase + r] = (u16)mv;
      ++r;
      const int np = ++p[best];
      v[best] = (np < C[best]) ? (int)L[best][np] : 0x10000;
    }
    ccntb[(h << 9) + b] = r;
  }

  // Phase D: query hist (bins [lo, lo+256))
  for (int i = tid; i < N_TOK; i += 256) {
    const int sl = (int)qbs[i] - lo;
    if (sl >= 0 && sl < 256) {
      const int p = atomicAdd(&qh[sl], 1);
      if (p < QCAP) qlist[(((h << 9) + lo + sl) << 7) + p] = (u16)i;
    }
  }
  __syncthreads();
  for (int i = tid; i < 256; i += 256)
    qhist[(h << 9) + lo + i] = qh[i] < QCAP ? qh[i] : QCAP;
}

// ---------------------------------------------------------------------------
// Bin-batched MFMA attention (R8-verified layouts); K/Q now bf16 source ->
// uint4 gathers, zero conversions.
// ---------------------------------------------------------------------------
__global__ __launch_bounds__(64) void attn_bin_kernel(
    const u16* __restrict__ Qb, const u16* __restrict__ Kb,
    const u16* __restrict__ Vb, const int* __restrict__ qhist,
    const u16* __restrict__ qlist, const int* __restrict__ ccntb,
    const u16* __restrict__ candb, u16* __restrict__ aout)
{
  __shared__ u16 kf[4 * 2 * 4 * 16 * 8];
  __shared__ u16 vf[4 * 2 * 4 * 16 * 8];
  __shared__ u16 pf[16 * 72];
  __shared__ u16 s_cand[64];
  __shared__ int s_qg[16];

  const int hb = blockIdx.x;
  const int h = hb >> 9;
  const int qcnt = qhist[hb];
  if (qcnt == 0) return;

  const int lane = threadIdx.x;
  const int l15 = lane & 15;
  const int quad = lane >> 4;

  const int ccnt = ccntb[hb];
  const int ccnt_eff = (ccnt == 0) ? 64 : ccnt;
  s_cand[lane] = (ccnt == 0) ? (u16)lane
               : ((lane < ccnt) ? candb[(hb << 6) + lane] : candb[hb << 6]);
  __syncthreads();

  // K gather: 8 rows x 8 segs(16B=8 bf16) per iteration, direct A-frag store
  {
    const int r = lane >> 3, s = lane & 7;
    const int ks = s >> 2, qd = s & 3;
#pragma unroll
    for (int it = 0; it < 8; ++it) {
      const int key = it * 8 + r;
      const int c = s_cand[key];
      const uint4 kv = *(const uint4*)(Kb + ((h << 18) | (c << 6)) + s * 8);
      const int idx = ((((key >> 4) * 2 + ks) * 4 + qd) * 16 + (key & 15)) * 8;
      *(uint4*)&kf[idx] = kv;
    }
  }
  // V gather -> B-frag order
  {
    const int r = lane >> 3, s = lane & 7;
    const int nt = s >> 1, d0 = (s & 1) * 8;
#pragma unroll
    for (int it = 0; it < 8; ++it) {
      const int key = it * 8 + r;
      const int c = s_cand[key];
      union { u16 hh[8]; uint4 u; } vv;
      vv.u = *(const uint4*)(Vb + ((h << 18) | (c << 6)) + s * 8);
      const int kstep = key >> 5, qd = (key >> 3) & 3, j = key & 7;
#pragma unroll
      for (int m = 0; m < 8; ++m)
        vf[(((nt * 2 + kstep) * 4 + qd) * 16 + d0 + m) * 8 + j] = vv.hh[m];
    }
  }
  __syncthreads();

  v8bf akf[4][2], bvf[4][2];
#pragma unroll
  for (int t = 0; t < 4; ++t)
#pragma unroll
    for (int ks = 0; ks < 2; ++ks) {
      akf[t][ks] = *(const v8bf*)&kf[(((t * 2 + ks) * 4 + quad) * 16 + l15) * 8];
      bvf[t][ks] = *(const v8bf*)&vf[(((t * 2 + ks) * 4 + quad) * 16 + l15) * 8];
    }

  const int nchunk = (qcnt + 15) >> 4;
  for (int ci = 0; ci < nchunk; ++ci) {
    const int base = ci << 4;
    const int qcn = min(16, qcnt - base);
    __syncthreads();
    if (lane < 16) {
      int idx = base + lane;
      if (idx > qcnt - 1) idx = qcnt - 1;
      s_qg[lane] = (int)qlist[(hb << 7) + idx];
    }
    __syncthreads();

    const u16* qrow = Qb + ((h << 18) | (s_qg[l15] << 6));
    v8bf bq[2];
#pragma unroll
    for (int ks = 0; ks < 2; ++ks)
      bq[ks] = *(const v8bf*)(qrow + ks * 32 + quad * 8);

    float sc[16];
#pragma unroll
    for (int t = 0; t < 4; ++t) {
      f32x4 sa = {0.f, 0.f, 0.f, 0.f};
      sa = __builtin_amdgcn_mfma_f32_16x16x32_bf16(akf[t][0], bq[0], sa, 0, 0, 0);
      sa = __builtin_amdgcn_mfma_f32_16x16x32_bf16(akf[t][1], bq[1], sa, 0, 0, 0);
#pragma unroll
      for (int r = 0; r < 4; ++r) {
        const int key = t * 16 + quad * 4 + r;
        sc[t * 4 + r] = (key < ccnt_eff) ? sa[r] * ATT_SCALE : -INFINITY;
      }
    }
    float mx = sc[0];
#pragma unroll
    for (int i = 1; i < 16; ++i) mx = fmaxf(mx, sc[i]);
    mx = fmaxf(mx, __shfl_xor(mx, 16));
    mx = fmaxf(mx, __shfl_xor(mx, 32));
    float sum = 0.0f;
    float pe[16];
#pragma unroll
    for (int i = 0; i < 16; ++i) { pe[i] = __expf(sc[i] - mx); sum += pe[i]; }
    sum += __shfl_xor(sum, 16);
    sum += __shfl_xor(sum, 32);
    const float inv = 1.0f / sum;

    __syncthreads();
#pragma unroll
    for (int t = 0; t < 4; ++t)
#pragma unroll
      for (int r = 0; r < 4; ++r)
        pf[l15 * 72 + t * 16 + quad * 4 + r] = f2bf(pe[t * 4 + r] * inv);
    __syncthreads();

    v8bf ap[2];
#pragma unroll
    for (int ks = 0; ks < 2; ++ks)
      ap[ks] = *(const v8bf*)&pf[l15 * 72 + ks * 32 + quad * 8];

#pragma unroll
    for (int nt = 0; nt < 4; ++nt) {
      f32x4 o = {0.f, 0.f, 0.f, 0.f};
      o = __builtin_amdgcn_mfma_f32_16x16x32_bf16(ap[0], bvf[nt][0], o, 0, 0, 0);
      o = __builtin_amdgcn_mfma_f32_16x16x32_bf16(ap[1], bvf[nt][1], o, 0, 0, 0);
#pragma unroll
      for (int r = 0; r < 4; ++r) {
        const int row = quad * 4 + r;
        if (row < qcn)
          aout[s_qg[row] * DMODEL + (h << 6) + nt * 16 + l15] = f2bf(o[r]);
      }
    }
  }
}

extern "C" void kernel_launch(void* const* d_in, const int* in_sizes, int n_in,
                              void* d_out, int out_size, void* d_ws, size_t ws_size,
                              hipStream_t stream) {
  const float* query = (const float*)d_in[0];
  const float* key_  = (const float*)d_in[1];
  const float* value = (const float*)d_in[2];
  const float* Wq = (const float*)d_in[3];
  const float* bq = (const float*)d_in[4];
  const float* Wk = (const float*)d_in[5];
  const float* bk = (const float*)d_in[6];
  const float* Wv = (const float*)d_in[7];
  const float* bv = (const float*)d_in[8];
  const float* Wo = (const float*)d_in[9];
  const float* bo = (const float*)d_in[10];

  char* ws = (char*)d_ws;
  u16* qx    = (u16*)(ws);                   // 4 MB  [n][512] bf16 query
  u16* kx    = (u16*)(ws + 4194304);         // 4 MB
  u16* vx    = (u16*)(ws + 8388608);         // 4 MB
  u16* wqx   = (u16*)(ws + 12582912);        // 512 KB
  u16* wkx   = (u16*)(ws + 13107200);        // 512 KB
  u16* wvx   = (u16*)(ws + 13631488);        // 512 KB
  u16* wox   = (u16*)(ws + 14155776);        // 512 KB
  u16* Qb    = (u16*)(ws + 14680064);        // 4 MB  [h][n][64] bf16 projected
  u16* Kb    = (u16*)(ws + 18874368);        // 4 MB
  u16* Vb    = (u16*)(ws + 23068672);        // 4 MB
  u16* aout  = (u16*)(ws + 27262976);        // 4 MB  [n][512] bf16
  int* qb    = (int*)(ws + 31457280);        // 128 KB
  int* kb    = (int*)(ws + 31588352);        // 128 KB
  unsigned char* flags = (unsigned char*)(ws + 31719424);  // 64 KB
  int* qhist = (int*)(ws + 31784960);        // 16 KB
  int* ccntb = (int*)(ws + 31801344);        // 16 KB
  u16* qlist = (u16*)(ws + 31817728);        // 1 MB  [4096][128]
  u16* candb = (u16*)(ws + 32866304);        // 512 KB [4096][64]
  // total ~31.9 MB

  prep_kernel<<<4096, 256, 0, stream>>>(
      query, key_, value, Wq, Wk, Wv, Wo,
      qx, kx, vx, wqx, wkx, wvx, wox, qb, kb, flags);
  gemm_qkv_kernel<<<dim3(32, 4, 3), 256, 0, stream>>>(
      qx, kx, vx, wqx, wkx, wvx, bq, bk, bv, Qb, Kb, Vb);
  combo_kernel<<<16, 256, 0, stream>>>(
      query, key_, Wq, Wk, qb, kb, flags, qhist, qlist, ccntb, candb);
  attn_bin_kernel<<<4096, 64, 0, stream>>>(
      Qb, Kb, Vb, qhist, qlist, ccntb, candb, aout);
  gemm_out_kernel<<<dim3(32, 4), 256, 0, stream>>>(aout, wox, bo, (float*)d_out);
}

// Round 10
// 218.117 us; speedup vs baseline: 1.3092x; 1.3092x over previous
//
#include <hip/hip_runtime.h>
#include <math.h>

typedef unsigned short u16;
typedef __attribute__((ext_vector_type(8))) short v8bf;
typedef __attribute__((ext_vector_type(4))) float f32x4;

#define N_TOK 4096
#define DMODEL 512
#define NHEAD 8
#define HDIM 64
#define CANDN 64
#define NBINS 512
#define BINCAP 64
#define QCAP 128
#define ATT_SCALE 0.125f
#define MAX_NORM_F 0.99999f
#define WL_CAP 8192

__device__ __forceinline__ float bf2f(u16 u) {
  union { unsigned int i; float f; } v; v.i = ((unsigned int)u) << 16; return v.f;
}
__device__ __forceinline__ u16 f2bf(float f) {
  union { float f; unsigned int i; } v; v.f = f;
  unsigned int x = v.i;
  return (u16)((x + 0x7fffu + ((x >> 16) & 1u)) >> 16);
}
__device__ __forceinline__ uint4 load_pack8(const float* __restrict__ p) {
  const float4 x0 = *(const float4*)p;
  const float4 x1 = *(const float4*)(p + 4);
  union { u16 h[8]; uint4 u; } r;
  r.h[0] = f2bf(x0.x); r.h[1] = f2bf(x0.y); r.h[2] = f2bf(x0.z); r.h[3] = f2bf(x0.w);
  r.h[4] = f2bf(x1.x); r.h[5] = f2bf(x1.y); r.h[6] = f2bf(x1.z); r.h[7] = f2bf(x1.w);
  return r.u;
}

// ---------------------------------------------------------------------------
// prep: blocks 0..511 = bins pass 1 (f64 dots, boundary-risk -> wl append;
// wl_count zeroed via hipMemsetAsync). Blocks 512..4095 = f32->bf16 convert
// of all GEMM operands (same RNE point as before -> bit-identical).
// ---------------------------------------------------------------------------
__global__ __launch_bounds__(256) void prep_kernel(
    const float* __restrict__ query, const float* __restrict__ key_,
    const float* __restrict__ value,
    const float* __restrict__ Wq, const float* __restrict__ Wk,
    const float* __restrict__ Wv, const float* __restrict__ Wo,
    u16* __restrict__ qx, u16* __restrict__ kx, u16* __restrict__ vx,
    u16* __restrict__ wqx, u16* __restrict__ wkx, u16* __restrict__ wvx,
    u16* __restrict__ wox,
    int* __restrict__ qb, int* __restrict__ kb,
    int* __restrict__ wl_count, int* __restrict__ wl)
{
  __shared__ float xs[16 * 516];
  const int blk = blockIdx.x;
  const int tid = threadIdx.x;

  if (blk >= 512) {  // convert path
    const int rel = blk - 512;
    const float* src; u16* dst; int base;
    if (rel < 1024)      { src = query; dst = qx; base = rel << 11; }
    else if (rel < 2048) { src = key_;  dst = kx; base = (rel - 1024) << 11; }
    else if (rel < 3072) { src = value; dst = vx; base = (rel - 2048) << 11; }
    else {
      const int r2 = rel - 3072; const int w = r2 >> 7;
      src = (w == 0) ? Wq : (w == 1) ? Wk : (w == 2) ? Wv : Wo;
      dst = (w == 0) ? wqx : (w == 1) ? wkx : (w == 2) ? wvx : wox;
      base = (r2 & 127) << 11;
    }
    const int off = base + tid * 8;
    *(uint4*)(dst + off) = load_pack8(src + off);
    return;
  }

  // bins pass 1: 16-row LDS tile, 16 threads share a row (coalesced)
  const int isk  = blk >> 8;
  const int tile = blk & 255;
  const float* X = isk ? key_ : query;
  const float* W = isk ? Wk : Wq;

#pragma unroll
  for (int i = 0; i < 8; ++i) {
    const int flat = i * 1024 + tid * 4;
    const int row = flat >> 9, col = flat & 511;
    *(float4*)&xs[row * 516 + col] = *(const float4*)(X + (tile * 16 + row) * DMODEL + col);
  }
  __syncthreads();

  const int n_local = tid >> 4;
  const int pair = tid & 15;
  const int h = pair >> 1, coord = pair & 1;
  const float* wrow = W + ((h << 6) + coord) * DMODEL;
  const float* xrow = &xs[n_local * 516];

  double c0 = 0.0, c1 = 0.0, c2 = 0.0, c3 = 0.0;
  for (int k = 0; k < DMODEL; k += 4) {
    const float4 xv = *(const float4*)(xrow + k);
    const float4 wv = *(const float4*)(wrow + k);
    c0 = fma((double)xv.x, (double)wv.x, c0);
    c1 = fma((double)xv.y, (double)wv.y, c1);
    c2 = fma((double)xv.z, (double)wv.z, c2);
    c3 = fma((double)xv.w, (double)wv.w, c3);
  }
  const double a = (c0 + c1) + (c2 + c3);
  const double other = __shfl_xor(a, 1);
  if (coord == 0) {
    const double a0 = a, a1 = other;
    const int n = tile * 16 + n_local;
    double ang = atan2(a1, a0);
    double t = (ang / 6.283185307179586 + 0.5) * 512.0;
    int b = (int)floor(t);
    b = b < 0 ? 0 : (b > 511 ? 511 : b);
    (isk ? kb : qb)[(h << 12) + n] = b;

    const double r = sqrt(a0 * a0 + a1 * a1);
    const double dist = fabs(t - nearbyint(t));
    const double margin = fmin(0.45, 3.3e-4 / fmax(r, 1e-30) + 5e-5);
    if (dist < margin) {
      int idx = atomicAdd(wl_count, 1);
      if (idx < WL_CAP) wl[idx] = (isk << 15) | (h << 12) | n;
    }
  }
}

// ---------------------------------------------------------------------------
// GEMM 128x128 tile, BK=32, pure bf16 operands (preconverted).
// Poincare projection fused into Q/K epilogue; outputs stored bf16.
// ---------------------------------------------------------------------------
__global__ __launch_bounds__(256) void gemm_qkv_kernel(
    const u16* __restrict__ qx, const u16* __restrict__ kx, const u16* __restrict__ vx,
    const u16* __restrict__ wqx, const u16* __restrict__ wkx, const u16* __restrict__ wvx,
    const float* __restrict__ bq, const float* __restrict__ bk, const float* __restrict__ bv,
    u16* __restrict__ Qb, u16* __restrict__ Kb, u16* __restrict__ Vb)
{
  const int z = blockIdx.z;
  const u16* A    = (z == 0) ? qx : (z == 1) ? kx : vx;
  const u16* W    = (z == 0) ? wqx : (z == 1) ? wkx : wvx;
  const float* bias = (z == 0) ? bq : (z == 1) ? bk : bv;
  u16* O          = (z == 0) ? Qb : (z == 1) ? Kb : Vb;

  __shared__ u16 As[128 * 40];
  __shared__ u16 Ws[128 * 40];

  const int tid  = threadIdx.x;
  const int lane = tid & 63;
  const int wave = tid >> 6;
  const int row4 = tid >> 2;
  const int seg  = tid & 3;

  const int bm = blockIdx.x * 128;
  const int bn = blockIdx.y * 128;
  const int wm = (wave & 1) * 64;
  const int wn = (wave >> 1) * 64;
  const int l15 = lane & 15;
  const int quad = lane >> 4;

  f32x4 acc[4][4] = {};

  for (int kt = 0; kt < DMODEL; kt += 32) {
    uint4 a0 = *(const uint4*)(A + (bm + row4) * DMODEL + kt + seg * 8);
    uint4 a1 = *(const uint4*)(A + (bm + row4 + 64) * DMODEL + kt + seg * 8);
    uint4 w0 = *(const uint4*)(W + (bn + row4) * DMODEL + kt + seg * 8);
    uint4 w1 = *(const uint4*)(W + (bn + row4 + 64) * DMODEL + kt + seg * 8);
    __syncthreads();
    *(uint4*)&As[row4 * 40 + seg * 8] = a0;
    *(uint4*)&As[(row4 + 64) * 40 + seg * 8] = a1;
    *(uint4*)&Ws[row4 * 40 + seg * 8] = w0;
    *(uint4*)&Ws[(row4 + 64) * 40 + seg * 8] = w1;
    __syncthreads();
    v8bf af[4], bfr[4];
#pragma unroll
    for (int i = 0; i < 4; ++i)
      af[i] = *(const v8bf*)&As[(wm + i * 16 + l15) * 40 + quad * 8];
#pragma unroll
    for (int j = 0; j < 4; ++j)
      bfr[j] = *(const v8bf*)&Ws[(wn + j * 16 + l15) * 40 + quad * 8];
#pragma unroll
    for (int i = 0; i < 4; ++i)
#pragma unroll
      for (int j = 0; j < 4; ++j)
        acc[i][j] = __builtin_amdgcn_mfma_f32_16x16x32_bf16(af[i], bfr[j], acc[i][j], 0, 0, 0);
  }

  float bval[4];
#pragma unroll
  for (int j = 0; j < 4; ++j) bval[j] = bias[bn + wn + j * 16 + l15];
  const int h = (bn + wn) >> 6;

#pragma unroll
  for (int i = 0; i < 4; ++i) {
#pragma unroll
    for (int r = 0; r < 4; ++r) {
      const int row = bm + wm + i * 16 + quad * 4 + r;
      float v0 = acc[i][0][r] + bval[0];
      float v1 = acc[i][1][r] + bval[1];
      float v2 = acc[i][2][r] + bval[2];
      float v3 = acc[i][3][r] + bval[3];
      if (z != 2) {
        float ss = v0 * v0 + v1 * v1 + v2 * v2 + v3 * v3;
#pragma unroll
        for (int o = 1; o < 16; o <<= 1) ss += __shfl_xor(ss, o);
        const float s = fminf(1.0f, MAX_NORM_F / fmaxf(sqrtf(ss), 1e-12f));
        v0 *= s; v1 *= s; v2 *= s; v3 *= s;
      }
      const int base = (((h << 12) + row) << 6) + l15;
      O[base +  0] = f2bf(v0); O[base + 16] = f2bf(v1);
      O[base + 32] = f2bf(v2); O[base + 48] = f2bf(v3);
    }
  }
}

__global__ __launch_bounds__(256) void gemm_out_kernel(
    const u16* __restrict__ A, const u16* __restrict__ W,
    const float* __restrict__ bias, float* __restrict__ O)
{
  __shared__ u16 As[128 * 40];
  __shared__ u16 Ws[128 * 40];

  const int tid  = threadIdx.x;
  const int lane = tid & 63;
  const int wave = tid >> 6;
  const int row4 = tid >> 2;
  const int seg  = tid & 3;

  const int bm = blockIdx.x * 128;
  const int bn = blockIdx.y * 128;
  const int wm = (wave & 1) * 64;
  const int wn = (wave >> 1) * 64;
  const int l15 = lane & 15;
  const int quad = lane >> 4;

  f32x4 acc[4][4] = {};

  for (int kt = 0; kt < DMODEL; kt += 32) {
    uint4 a0 = *(const uint4*)(A + (bm + row4) * DMODEL + kt + seg * 8);
    uint4 a1 = *(const uint4*)(A + (bm + row4 + 64) * DMODEL + kt + seg * 8);
    uint4 w0 = *(const uint4*)(W + (bn + row4) * DMODEL + kt + seg * 8);
    uint4 w1 = *(const uint4*)(W + (bn + row4 + 64) * DMODEL + kt + seg * 8);
    __syncthreads();
    *(uint4*)&As[row4 * 40 + seg * 8] = a0;
    *(uint4*)&As[(row4 + 64) * 40 + seg * 8] = a1;
    *(uint4*)&Ws[row4 * 40 + seg * 8] = w0;
    *(uint4*)&Ws[(row4 + 64) * 40 + seg * 8] = w1;
    __syncthreads();
    v8bf af[4], bfr[4];
#pragma unroll
    for (int i = 0; i < 4; ++i)
      af[i] = *(const v8bf*)&As[(wm + i * 16 + l15) * 40 + quad * 8];
#pragma unroll
    for (int j = 0; j < 4; ++j)
      bfr[j] = *(const v8bf*)&Ws[(wn + j * 16 + l15) * 40 + quad * 8];
#pragma unroll
    for (int i = 0; i < 4; ++i)
#pragma unroll
      for (int j = 0; j < 4; ++j)
        acc[i][j] = __builtin_amdgcn_mfma_f32_16x16x32_bf16(af[i], bfr[j], acc[i][j], 0, 0, 0);
  }

#pragma unroll
  for (int j = 0; j < 4; ++j) {
    const int cg = bn + wn + j * 16 + l15;
    const float bval = bias[cg];
#pragma unroll
    for (int i = 0; i < 4; ++i) {
      const int rbase = bm + wm + i * 16 + quad * 4;
#pragma unroll
      for (int r = 0; r < 4; ++r)
        O[(rbase + r) * DMODEL + cg] = acc[i][j][r] + bval;
    }
  }
}

// --------------------------- fdlibm ports (R5-verified) --------------------
__device__ float fdlibm_atanf(float x) {
#pragma clang fp contract(off)
  const float atanhi[4] = {4.6364760399e-01f, 7.8539812565e-01f,
                           9.8279368877e-01f, 1.5707962513e+00f};
  const float atanlo[4] = {5.0121582440e-09f, 3.7748947079e-08f,
                           3.4473217170e-08f, 7.5497894159e-08f};
  const float aT[5] = {3.3333328366e-01f, -1.9999158382e-01f, 1.4253635705e-01f,
                       -1.0648017377e-01f, 6.1687607318e-02f};
  unsigned ix = __float_as_uint(x);
  const unsigned sign = ix >> 31;
  ix &= 0x7fffffffu;
  int id;
  float z, w, s1, s2;
  if (ix >= 0x4c800000u) {
    z = atanhi[3] + 0x1p-120f;
    return sign ? -z : z;
  }
  if (ix < 0x3ee00000u) {
    if (ix < 0x39800000u) return x;
    id = -1;
  } else {
    x = fabsf(x);
    if (ix < 0x3f980000u) {
      if (ix < 0x3f300000u) { id = 0; x = (2.0f * x - 1.0f) / (2.0f + x); }
      else                  { id = 1; x = (x - 1.0f) / (x + 1.0f); }
    } else {
      if (ix < 0x401c0000u) { id = 2; x = (x - 1.5f) / (1.0f + 1.5f * x); }
      else                  { id = 3; x = -1.0f / x; }
    }
  }
  z = x * x;
  w = z * z;
  s1 = z * (aT[0] + w * (aT[2] + w * aT[4]));
  s2 = w * (aT[1] + w * aT[3]);
  if (id < 0) return x - x * (s1 + s2);
  z = atanhi[id] - ((x * (s1 + s2) - atanlo[id]) - x);
  return sign ? -z : z;
}

__device__ float fdlibm_atan2f(float y, float x) {
#pragma clang fp contract(off)
  const float pi = 3.1415927410e+00f, pi_lo = -8.7422776573e-08f;
  const unsigned hx = __float_as_uint(x), hy = __float_as_uint(y);
  if (hx == 0x3f800000u) return fdlibm_atanf(y);
  const unsigned m = ((hy >> 31) & 1u) | ((hx >> 30) & 2u);
  const unsigned ix = hx & 0x7fffffffu, iy = hy & 0x7fffffffu;
  if (iy == 0u) {
    switch (m) { case 0: case 1: return y; case 2: return pi; default: return -pi; }
  }
  if (ix == 0u) return (m & 1u) ? -1.57079637050628662f : 1.57079637050628662f;
  float z;
  if (ix + (26u << 23) < iy) {
    z = 1.57079637050628662f;
    return (m & 1u) ? -z : z;
  }
  if ((m & 2u) && iy + (26u << 23) < ix) z = 0.0f;
  else z = fdlibm_atanf(fabsf(y / x));
  switch (m) {
    case 0: return z;
    case 1: return -z;
    case 2: return pi - (z - pi_lo);
    default: return (z - pi_lo) - pi;
  }
}

// np-f32 bit-mimic fix of flagged elements (R8-verified, 64 blocks).
__global__ __launch_bounds__(256) void bins_pass2_kernel(
    const float* __restrict__ query, const float* __restrict__ key_,
    const float* __restrict__ Wq, const float* __restrict__ Wk,
    int* __restrict__ qb, int* __restrict__ kb,
    const int* __restrict__ wl_count, const int* __restrict__ wl)
{
  int cnt_ = *wl_count;
  if (cnt_ > WL_CAP) cnt_ = WL_CAP;
  const int w = threadIdx.x >> 6;
  const int d = threadIdx.x & 63;
  for (int e = blockIdx.x * 4 + w; e < cnt_; e += gridDim.x * 4) {
    const int code = wl[e];
    const int n = code & 4095;
    const int h = (code >> 12) & 7;
    const int isk = (code >> 15) & 1;
    const float* xr = (isk ? key_ : query) + n * DMODEL;
    const float* wr = (isk ? Wk : Wq) + ((h << 6) + d) * DMODEL;
    float acc = 0.0f;
    for (int k = 0; k < DMODEL; k += 16) {
      const float4 xa = *(const float4*)(xr + k);
      const float4 xb = *(const float4*)(xr + k + 4);
      const float4 xc = *(const float4*)(xr + k + 8);
      const float4 xd = *(const float4*)(xr + k + 12);
      const float4 wa = *(const float4*)(wr + k);
      const float4 wb = *(const float4*)(wr + k + 4);
      const float4 wc = *(const float4*)(wr + k + 8);
      const float4 wd = *(const float4*)(wr + k + 12);
      acc = __fmaf_rn(xa.x, wa.x, acc); acc = __fmaf_rn(xa.y, wa.y, acc);
      acc = __fmaf_rn(xa.z, wa.z, acc); acc = __fmaf_rn(xa.w, wa.w, acc);
      acc = __fmaf_rn(xb.x, wb.x, acc); acc = __fmaf_rn(xb.y, wb.y, acc);
      acc = __fmaf_rn(xb.z, wb.z, acc); acc = __fmaf_rn(xb.w, wb.w, acc);
      acc = __fmaf_rn(xc.x, wc.x, acc); acc = __fmaf_rn(xc.y, wc.y, acc);
      acc = __fmaf_rn(xc.z, wc.z, acc); acc = __fmaf_rn(xc.w, wc.w, acc);
      acc = __fmaf_rn(xd.x, wd.x, acc); acc = __fmaf_rn(xd.y, wd.y, acc);
      acc = __fmaf_rn(xd.z, wd.z, acc); acc = __fmaf_rn(xd.w, wd.w, acc);
    }
    {
#pragma clang fp contract(off)
      const float sq = acc * acc;
      float rr[8];
#pragma unroll
      for (int j = 0; j < 8; ++j) rr[j] = __shfl(sq, j);
      for (int i = 8; i < 64; i += 8) {
#pragma unroll
        for (int j = 0; j < 8; ++j) rr[j] += __shfl(sq, i + j);
      }
      const float ss = ((rr[0] + rr[1]) + (rr[2] + rr[3])) +
                       ((rr[4] + rr[5]) + (rr[6] + rr[7]));
      const float nrm = __fsqrt_rn(ss);
      const float s = fminf(1.0f, 0.99999f / fmaxf(nrm, 1e-12f));
      const float c0 = __shfl(acc, 0) * s;
      const float c1 = __shfl(acc, 1) * s;
      const float cr = (float)atan2((double)c1, (double)c0);
      const float fd = fdlibm_atan2f(c1, c0);
      const float tol = fmaxf(fabsf(cr) * 6e-7f, 1e-30f);
      const float ang = (fabsf(fd - cr) <= tol) ? fd : cr;
      const float t = ((ang / 6.2831854820251465f) + 0.5f) * 512.0f;
      int b = (int)floorf(t);
      b = b < 0 ? 0 : (b > 511 ? 511 : b);
      if (d == 0) (isk ? kb : qb)[(h << 12) + n] = b;
    }
  }
}

// Histogram keys and queries into per-(h,bin) lists. Appends are UNORDERED —
// the select kernel is order-invariant (rank-based).
__global__ __launch_bounds__(256) void bin_hist_kernel(
    const int* __restrict__ kb, const int* __restrict__ qb,
    int* __restrict__ khist, u16* __restrict__ blist,
    int* __restrict__ qhist, u16* __restrict__ qlist)
{
  const int h = blockIdx.x;
  const int type = blockIdx.y;  // 0 = keys, 1 = queries
  const int* src = type ? qb : kb;
  int* hist = type ? qhist : khist;
  u16* list = type ? qlist : blist;
  const int cap = type ? QCAP : BINCAP;

  __shared__ int lhist[NBINS];
  for (int i = threadIdx.x; i < NBINS; i += 256) lhist[i] = 0;
  __syncthreads();
  for (int i = threadIdx.x; i < N_TOK; i += 256) {
    const int b = src[(h << 12) + i];
    const int pos = atomicAdd(&lhist[b], 1);
    if (pos < cap) list[((h << 9) + b) * cap + pos] = (u16)i;
  }
  __syncthreads();
  for (int i = threadIdx.x; i < NBINS; i += 256)
    hist[(h << 9) + i] = lhist[i] < cap ? lhist[i] : cap;
}

// ---------------------------------------------------------------------------
// Rank-based candidate selection (R9 post-mortem: serial merges/sorts were
// latency chains). One wave per (h,bin): load the 3 neighbor bins' UNORDERED
// lists (lane l holds up to 3 elements, 0xFFFF-padded); each element's rank
// in the union = count of union elements strictly smaller (all values
// distinct). rank < CANDN -> candb[rank]. Bit-identical output to the old
// sort+merge (index-sorted first-64 of the union). Pure shfl/VALU.
// ---------------------------------------------------------------------------
__global__ __launch_bounds__(256) void select_kernel(
    const int* __restrict__ khist, const u16* __restrict__ blist,
    int* __restrict__ ccntb, u16* __restrict__ candb)
{
  const int hb = blockIdx.x * 4 + (threadIdx.x >> 6);  // 0..4095
  const int lane = threadIdx.x & 63;
  const int h = hb >> 9;
  const int b = hb & 511;

  int v0 = 0xFFFF, v1 = 0xFFFF, v2 = 0xFFFF;
  int c0 = 0, c1 = 0, c2 = 0;
  {
    const int bb = b - 1;
    if (bb >= 0) {
      c0 = khist[(h << 9) + bb];
      if (lane < c0) v0 = (int)blist[(((h << 9) + bb) << 6) + lane];
    }
  }
  {
    c1 = khist[(h << 9) + b];
    if (lane < c1) v1 = (int)blist[(((h << 9) + b) << 6) + lane];
  }
  {
    const int bb = b + 1;
    if (bb < NBINS) {
      c2 = khist[(h << 9) + bb];
      if (lane < c2) v2 = (int)blist[(((h << 9) + bb) << 6) + lane];
    }
  }

  int r0 = 0, r1 = 0, r2 = 0;
#pragma unroll 8
  for (int j = 0; j < 64; ++j) {
    const int w0 = __shfl(v0, j);
    const int w1 = __shfl(v1, j);
    const int w2 = __shfl(v2, j);
    r0 += (w0 < v0) + (w1 < v0) + (w2 < v0);
    r1 += (w0 < v1) + (w1 < v1) + (w2 < v1);
    r2 += (w0 < v2) + (w1 < v2) + (w2 < v2);
  }

  u16* out = candb + (hb << 6);
  if (v0 != 0xFFFF && r0 < CANDN) out[r0] = (u16)v0;
  if (v1 != 0xFFFF && r1 < CANDN) out[r1] = (u16)v1;
  if (v2 != 0xFFFF && r2 < CANDN) out[r2] = (u16)v2;
  if (lane == 0) {
    const int tot = c0 + c1 + c2;
    ccntb[hb] = tot < CANDN ? tot : CANDN;
  }
}

// ---------------------------------------------------------------------------
// Bin-batched MFMA attention (R8/R9-verified layouts, bf16 sources).
// ---------------------------------------------------------------------------
__global__ __launch_bounds__(64) void attn_bin_kernel(
    const u16* __restrict__ Qb, const u16* __restrict__ Kb,
    const u16* __restrict__ Vb, const int* __restrict__ qhist,
    const u16* __restrict__ qlist, const int* __restrict__ ccntb,
    const u16* __restrict__ candb, u16* __restrict__ aout)
{
  __shared__ u16 kf[4 * 2 * 4 * 16 * 8];
  __shared__ u16 vf[4 * 2 * 4 * 16 * 8];
  __shared__ u16 pf[16 * 72];
  __shared__ u16 s_cand[64];
  __shared__ int s_qg[16];

  const int hb = blockIdx.x;
  const int h = hb >> 9;
  const int qcnt = qhist[hb];
  if (qcnt == 0) return;

  const int lane = threadIdx.x;
  const int l15 = lane & 15;
  const int quad = lane >> 4;

  const int ccnt = ccntb[hb];
  const int ccnt_eff = (ccnt == 0) ? 64 : ccnt;
  s_cand[lane] = (ccnt == 0) ? (u16)lane
               : ((lane < ccnt) ? candb[(hb << 6) + lane] : candb[hb << 6]);
  __syncthreads();

  {
    const int r = lane >> 3, s = lane & 7;
    const int ks = s >> 2, qd = s & 3;
#pragma unroll
    for (int it = 0; it < 8; ++it) {
      const int key = it * 8 + r;
      const int c = s_cand[key];
      const uint4 kv = *(const uint4*)(Kb + ((h << 18) | (c << 6)) + s * 8);
      const int idx = ((((key >> 4) * 2 + ks) * 4 + qd) * 16 + (key & 15)) * 8;
      *(uint4*)&kf[idx] = kv;
    }
  }
  {
    const int r = lane >> 3, s = lane & 7;
    const int nt = s >> 1, d0 = (s & 1) * 8;
#pragma unroll
    for (int it = 0; it < 8; ++it) {
      const int key = it * 8 + r;
      const int c = s_cand[key];
      union { u16 hh[8]; uint4 u; } vv;
      vv.u = *(const uint4*)(Vb + ((h << 18) | (c << 6)) + s * 8);
      const int kstep = key >> 5, qd = (key >> 3) & 3, j = key & 7;
#pragma unroll
      for (int m = 0; m < 8; ++m)
        vf[(((nt * 2 + kstep) * 4 + qd) * 16 + d0 + m) * 8 + j] = vv.hh[m];
    }
  }
  __syncthreads();

  v8bf akf[4][2], bvf[4][2];
#pragma unroll
  for (int t = 0; t < 4; ++t)
#pragma unroll
    for (int ks = 0; ks < 2; ++ks) {
      akf[t][ks] = *(const v8bf*)&kf[(((t * 2 + ks) * 4 + quad) * 16 + l15) * 8];
      bvf[t][ks] = *(const v8bf*)&vf[(((t * 2 + ks) * 4 + quad) * 16 + l15) * 8];
    }

  const int nchunk = (qcnt + 15) >> 4;
  for (int ci = 0; ci < nchunk; ++ci) {
    const int base = ci << 4;
    const int qcn = min(16, qcnt - base);
    __syncthreads();
    if (lane < 16) {
      int idx = base + lane;
      if (idx > qcnt - 1) idx = qcnt - 1;
      s_qg[lane] = (int)qlist[(hb << 7) + idx];
    }
    __syncthreads();

    const u16* qrow = Qb + ((h << 18) | (s_qg[l15] << 6));
    v8bf bq[2];
#pragma unroll
    for (int ks = 0; ks < 2; ++ks)
      bq[ks] = *(const v8bf*)(qrow + ks * 32 + quad * 8);

    float sc[16];
#pragma unroll
    for (int t = 0; t < 4; ++t) {
      f32x4 sa = {0.f, 0.f, 0.f, 0.f};
      sa = __builtin_amdgcn_mfma_f32_16x16x32_bf16(akf[t][0], bq[0], sa, 0, 0, 0);
      sa = __builtin_amdgcn_mfma_f32_16x16x32_bf16(akf[t][1], bq[1], sa, 0, 0, 0);
#pragma unroll
      for (int r = 0; r < 4; ++r) {
        const int key = t * 16 + quad * 4 + r;
        sc[t * 4 + r] = (key < ccnt_eff) ? sa[r] * ATT_SCALE : -INFINITY;
      }
    }
    float mx = sc[0];
#pragma unroll
    for (int i = 1; i < 16; ++i) mx = fmaxf(mx, sc[i]);
    mx = fmaxf(mx, __shfl_xor(mx, 16));
    mx = fmaxf(mx, __shfl_xor(mx, 32));
    float sum = 0.0f;
    float pe[16];
#pragma unroll
    for (int i = 0; i < 16; ++i) { pe[i] = __expf(sc[i] - mx); sum += pe[i]; }
    sum += __shfl_xor(sum, 16);
    sum += __shfl_xor(sum, 32);
    const float inv = 1.0f / sum;

    __syncthreads();
#pragma unroll
    for (int t = 0; t < 4; ++t)
#pragma unroll
      for (int r = 0; r < 4; ++r)
        pf[l15 * 72 + t * 16 + quad * 4 + r] = f2bf(pe[t * 4 + r] * inv);
    __syncthreads();

    v8bf ap[2];
#pragma unroll
    for (int ks = 0; ks < 2; ++ks)
      ap[ks] = *(const v8bf*)&pf[l15 * 72 + ks * 32 + quad * 8];

#pragma unroll
    for (int nt = 0; nt < 4; ++nt) {
      f32x4 o = {0.f, 0.f, 0.f, 0.f};
      o = __builtin_amdgcn_mfma_f32_16x16x32_bf16(ap[0], bvf[nt][0], o, 0, 0, 0);
      o = __builtin_amdgcn_mfma_f32_16x16x32_bf16(ap[1], bvf[nt][1], o, 0, 0, 0);
#pragma unroll
      for (int r = 0; r < 4; ++r) {
        const int row = quad * 4 + r;
        if (row < qcn)
          aout[s_qg[row] * DMODEL + (h << 6) + nt * 16 + l15] = f2bf(o[r]);
      }
    }
  }
}

extern "C" void kernel_launch(void* const* d_in, const int* in_sizes, int n_in,
                              void* d_out, int out_size, void* d_ws, size_t ws_size,
                              hipStream_t stream) {
  const float* query = (const float*)d_in[0];
  const float* key_  = (const float*)d_in[1];
  const float* value = (const float*)d_in[2];
  const float* Wq = (const float*)d_in[3];
  const float* bq = (const float*)d_in[4];
  const float* Wk = (const float*)d_in[5];
  const float* bk = (const float*)d_in[6];
  const float* Wv = (const float*)d_in[7];
  const float* bv = (const float*)d_in[8];
  const float* Wo = (const float*)d_in[9];
  const float* bo = (const float*)d_in[10];

  char* ws = (char*)d_ws;
  u16* qx    = (u16*)(ws);                   // 4 MB
  u16* kx    = (u16*)(ws + 4194304);         // 4 MB
  u16* vx    = (u16*)(ws + 8388608);         // 4 MB
  u16* wqx   = (u16*)(ws + 12582912);        // 512 KB
  u16* wkx   = (u16*)(ws + 13107200);        // 512 KB
  u16* wvx   = (u16*)(ws + 13631488);        // 512 KB
  u16* wox   = (u16*)(ws + 14155776);        // 512 KB
  u16* Qb    = (u16*)(ws + 14680064);        // 4 MB [h][n][64] bf16 projected
  u16* Kb    = (u16*)(ws + 18874368);        // 4 MB
  u16* Vb    = (u16*)(ws + 23068672);        // 4 MB
  u16* aout  = (u16*)(ws + 27262976);        // 4 MB [n][512] bf16
  int* qb    = (int*)(ws + 31457280);        // 128 KB
  int* kb    = (int*)(ws + 31588352);        // 128 KB
  int* wl_count = (int*)(ws + 31719424);     // 64 B
  int* wl    = (int*)(ws + 31719488);        // 32 KB
  int* khist = (int*)(ws + 31752256);        // 16 KB
  int* qhist = (int*)(ws + 31768640);        // 16 KB
  int* ccntb = (int*)(ws + 31785024);        // 16 KB
  u16* blist = (u16*)(ws + 31801408);        // 512 KB [4096][64]
  u16* qlist = (u16*)(ws + 32325696);        // 1 MB  [4096][128]
  u16* candb = (u16*)(ws + 33374272);        // 512 KB [4096][64]
  // total ~33.9 MB

  hipMemsetAsync(wl_count, 0, sizeof(int), stream);
  prep_kernel<<<4096, 256, 0, stream>>>(
      query, key_, value, Wq, Wk, Wv, Wo,
      qx, kx, vx, wqx, wkx, wvx, wox, qb, kb, wl_count, wl);
  gemm_qkv_kernel<<<dim3(32, 4, 3), 256, 0, stream>>>(
      qx, kx, vx, wqx, wkx, wvx, bq, bk, bv, Qb, Kb, Vb);
  bins_pass2_kernel<<<64, 256, 0, stream>>>(
      query, key_, Wq, Wk, qb, kb, wl_count, wl);
  bin_hist_kernel<<<dim3(8, 2), 256, 0, stream>>>(
      kb, qb, khist, blist, qhist, qlist);
  select_kernel<<<1024, 256, 0, stream>>>(khist, blist, ccntb, candb);
  attn_bin_kernel<<<4096, 64, 0, stream>>>(
      Qb, Kb, Vb, qhist, qlist, ccntb, candb, aout);
  gemm_out_kernel<<<dim3(32, 4), 256, 0, stream>>>(aout, wox, bo, (float*)d_out);
}

// Round 11
// 209.340 us; speedup vs baseline: 1.3641x; 1.0419x over previous
//
#include <hip/hip_runtime.h>
#include <math.h>

typedef unsigned short u16;
typedef __attribute__((ext_vector_type(8))) short v8bf;
typedef __attribute__((ext_vector_type(4))) float f32x4;

#define N_TOK 4096
#define DMODEL 512
#define NHEAD 8
#define HDIM 64
#define CANDN 64
#define NBINS 512
#define BINCAP 64
#define QCAP 128
#define ATT_SCALE 0.125f
#define MAX_NORM_F 0.99999f

__device__ __forceinline__ float bf2f(u16 u) {
  union { unsigned int i; float f; } v; v.i = ((unsigned int)u) << 16; return v.f;
}
__device__ __forceinline__ u16 f2bf(float f) {
  union { float f; unsigned int i; } v; v.f = f;
  unsigned int x = v.i;
  return (u16)((x + 0x7fffu + ((x >> 16) & 1u)) >> 16);
}
__device__ __forceinline__ uint4 load_pack8(const float* __restrict__ p) {
  const float4 x0 = *(const float4*)p;
  const float4 x1 = *(const float4*)(p + 4);
  union { u16 h[8]; uint4 u; } r;
  r.h[0] = f2bf(x0.x); r.h[1] = f2bf(x0.y); r.h[2] = f2bf(x0.z); r.h[3] = f2bf(x0.w);
  r.h[4] = f2bf(x1.x); r.h[5] = f2bf(x1.y); r.h[6] = f2bf(x1.z); r.h[7] = f2bf(x1.w);
  return r.u;
}

// ---------------------------------------------------------------------------
// prep: blocks 0..511 = bins pass 1 (f64 dots; boundary-risk -> flags byte,
// fully written -> no memset/atomic needed). Blocks 512..4095 = f32->bf16
// convert of all GEMM operands (same RNE point -> bit-identical numerics).
// ---------------------------------------------------------------------------
__global__ __launch_bounds__(256) void prep_kernel(
    const float* __restrict__ query, const float* __restrict__ key_,
    const float* __restrict__ value,
    const float* __restrict__ Wq, const float* __restrict__ Wk,
    const float* __restrict__ Wv, const float* __restrict__ Wo,
    u16* __restrict__ qx, u16* __restrict__ kx, u16* __restrict__ vx,
    u16* __restrict__ wqx, u16* __restrict__ wkx, u16* __restrict__ wvx,
    u16* __restrict__ wox,
    int* __restrict__ qb, int* __restrict__ kb, unsigned char* __restrict__ flags)
{
  __shared__ float xs[16 * 516];
  const int blk = blockIdx.x;
  const int tid = threadIdx.x;

  if (blk >= 512) {  // convert path
    const int rel = blk - 512;
    const float* src; u16* dst; int base;
    if (rel < 1024)      { src = query; dst = qx; base = rel << 11; }
    else if (rel < 2048) { src = key_;  dst = kx; base = (rel - 1024) << 11; }
    else if (rel < 3072) { src = value; dst = vx; base = (rel - 2048) << 11; }
    else {
      const int r2 = rel - 3072; const int w = r2 >> 7;
      src = (w == 0) ? Wq : (w == 1) ? Wk : (w == 2) ? Wv : Wo;
      dst = (w == 0) ? wqx : (w == 1) ? wkx : (w == 2) ? wvx : wox;
      base = (r2 & 127) << 11;
    }
    const int off = base + tid * 8;
    *(uint4*)(dst + off) = load_pack8(src + off);
    return;
  }

  // bins pass 1: 16-row LDS tile, 16 threads share a row (coalesced)
  const int isk  = blk >> 8;
  const int tile = blk & 255;
  const float* X = isk ? key_ : query;
  const float* W = isk ? Wk : Wq;

#pragma unroll
  for (int i = 0; i < 8; ++i) {
    const int flat = i * 1024 + tid * 4;
    const int row = flat >> 9, col = flat & 511;
    *(float4*)&xs[row * 516 + col] = *(const float4*)(X + (tile * 16 + row) * DMODEL + col);
  }
  __syncthreads();

  const int n_local = tid >> 4;
  const int pair = tid & 15;
  const int h = pair >> 1, coord = pair & 1;
  const float* wrow = W + ((h << 6) + coord) * DMODEL;
  const float* xrow = &xs[n_local * 516];

  double c0 = 0.0, c1 = 0.0, c2 = 0.0, c3 = 0.0;
  for (int k = 0; k < DMODEL; k += 4) {
    const float4 xv = *(const float4*)(xrow + k);
    const float4 wv = *(const float4*)(wrow + k);
    c0 = fma((double)xv.x, (double)wv.x, c0);
    c1 = fma((double)xv.y, (double)wv.y, c1);
    c2 = fma((double)xv.z, (double)wv.z, c2);
    c3 = fma((double)xv.w, (double)wv.w, c3);
  }
  const double a = (c0 + c1) + (c2 + c3);
  const double other = __shfl_xor(a, 1);
  if (coord == 0) {
    const double a0 = a, a1 = other;
    const int n = tile * 16 + n_local;
    double ang = atan2(a1, a0);
    double t = (ang / 6.283185307179586 + 0.5) * 512.0;
    int b = (int)floor(t);
    b = b < 0 ? 0 : (b > 511 ? 511 : b);
    (isk ? kb : qb)[(h << 12) + n] = b;

    const double r = sqrt(a0 * a0 + a1 * a1);
    const double dist = fabs(t - nearbyint(t));
    const double margin = fmin(0.45, 3.3e-4 / fmax(r, 1e-30) + 5e-5);
    flags[(isk << 15) | (h << 12) | n] = (dist < margin) ? 1 : 0;
  }
}

// --------------------------- fdlibm ports (R5-verified) --------------------
__device__ float fdlibm_atanf(float x) {
#pragma clang fp contract(off)
  const float atanhi[4] = {4.6364760399e-01f, 7.8539812565e-01f,
                           9.8279368877e-01f, 1.5707962513e+00f};
  const float atanlo[4] = {5.0121582440e-09f, 3.7748947079e-08f,
                           3.4473217170e-08f, 7.5497894159e-08f};
  const float aT[5] = {3.3333328366e-01f, -1.9999158382e-01f, 1.4253635705e-01f,
                       -1.0648017377e-01f, 6.1687607318e-02f};
  unsigned ix = __float_as_uint(x);
  const unsigned sign = ix >> 31;
  ix &= 0x7fffffffu;
  int id;
  float z, w, s1, s2;
  if (ix >= 0x4c800000u) {
    z = atanhi[3] + 0x1p-120f;
    return sign ? -z : z;
  }
  if (ix < 0x3ee00000u) {
    if (ix < 0x39800000u) return x;
    id = -1;
  } else {
    x = fabsf(x);
    if (ix < 0x3f980000u) {
      if (ix < 0x3f300000u) { id = 0; x = (2.0f * x - 1.0f) / (2.0f + x); }
      else                  { id = 1; x = (x - 1.0f) / (x + 1.0f); }
    } else {
      if (ix < 0x401c0000u) { id = 2; x = (x - 1.5f) / (1.0f + 1.5f * x); }
      else                  { id = 3; x = -1.0f / x; }
    }
  }
  z = x * x;
  w = z * z;
  s1 = z * (aT[0] + w * (aT[2] + w * aT[4]));
  s2 = w * (aT[1] + w * aT[3]);
  if (id < 0) return x - x * (s1 + s2);
  z = atanhi[id] - ((x * (s1 + s2) - atanlo[id]) - x);
  return sign ? -z : z;
}

__device__ float fdlibm_atan2f(float y, float x) {
#pragma clang fp contract(off)
  const float pi = 3.1415927410e+00f, pi_lo = -8.7422776573e-08f;
  const unsigned hx = __float_as_uint(x), hy = __float_as_uint(y);
  if (hx == 0x3f800000u) return fdlibm_atanf(y);
  const unsigned m = ((hy >> 31) & 1u) | ((hx >> 30) & 2u);
  const unsigned ix = hx & 0x7fffffffu, iy = hy & 0x7fffffffu;
  if (iy == 0u) {
    switch (m) { case 0: case 1: return y; case 2: return pi; default: return -pi; }
  }
  if (ix == 0u) return (m & 1u) ? -1.57079637050628662f : 1.57079637050628662f;
  float z;
  if (ix + (26u << 23) < iy) {
    z = 1.57079637050628662f;
    return (m & 1u) ? -z : z;
  }
  if ((m & 2u) && iy + (26u << 23) < ix) z = 0.0f;
  else z = fdlibm_atanf(fabsf(y / x));
  switch (m) {
    case 0: return z;
    case 1: return -z;
    case 2: return pi - (z - pi_lo);
    default: return (z - pi_lo) - pi;
  }
}

// ---------------------------------------------------------------------------
// gemmfix: blocks 0..383 = QKV GEMM (128x128 tile, BK=32, bf16 operands,
// Poincare clip fused in epilogue). Blocks 384..447 = binfix: each scans a
// 1024-flag slice; flagged elements re-derived with the np-f32 bit-mimic
// (one wave each). Fix rides free under the GEMM's runtime.
// ---------------------------------------------------------------------------
__global__ __launch_bounds__(256) void gemmfix_kernel(
    const u16* __restrict__ qx, const u16* __restrict__ kx, const u16* __restrict__ vx,
    const u16* __restrict__ wqx, const u16* __restrict__ wkx, const u16* __restrict__ wvx,
    const float* __restrict__ bq, const float* __restrict__ bk, const float* __restrict__ bv,
    const float* __restrict__ query, const float* __restrict__ key_,
    const float* __restrict__ Wq, const float* __restrict__ Wk,
    const unsigned char* __restrict__ flags,
    int* __restrict__ qb, int* __restrict__ kb,
    u16* __restrict__ Qb, u16* __restrict__ Kb, u16* __restrict__ Vb)
{
  __shared__ u16 As[128 * 40];
  __shared__ u16 Ws[128 * 40];
  __shared__ int wle[64];
  __shared__ int wlc;

  const int blk = blockIdx.x;
  const int tid = threadIdx.x;

  if (blk >= 384) {  // ---- binfix path ----
    const int slice = blk - 384;          // 0..63, covers 1024 flags
    if (tid == 0) wlc = 0;
    __syncthreads();
    for (int i = tid; i < 1024; i += 256) {
      const int flat = slice * 1024 + i;
      if (flags[flat]) {
        const int p = atomicAdd(&wlc, 1);
        if (p < 64) wle[p] = flat;
      }
    }
    __syncthreads();
    int nw = wlc; if (nw > 64) nw = 64;
    const int w = tid >> 6, d = tid & 63;
    for (int e = w; e < nw; e += 4) {
      const int flat = wle[e];
      const int n = flat & 4095;
      const int h = (flat >> 12) & 7;
      const int isk = flat >> 15;
      const float* xr = (isk ? key_ : query) + n * DMODEL;
      const float* wr = (isk ? Wk : Wq) + ((h << 6) + d) * DMODEL;
      float acc = 0.0f;
      for (int k = 0; k < DMODEL; k += 16) {
        const float4 xa = *(const float4*)(xr + k);
        const float4 xb = *(const float4*)(xr + k + 4);
        const float4 xc = *(const float4*)(xr + k + 8);
        const float4 xd = *(const float4*)(xr + k + 12);
        const float4 wa = *(const float4*)(wr + k);
        const float4 wb = *(const float4*)(wr + k + 4);
        const float4 wc = *(const float4*)(wr + k + 8);
        const float4 wd = *(const float4*)(wr + k + 12);
        acc = __fmaf_rn(xa.x, wa.x, acc); acc = __fmaf_rn(xa.y, wa.y, acc);
        acc = __fmaf_rn(xa.z, wa.z, acc); acc = __fmaf_rn(xa.w, wa.w, acc);
        acc = __fmaf_rn(xb.x, wb.x, acc); acc = __fmaf_rn(xb.y, wb.y, acc);
        acc = __fmaf_rn(xb.z, wb.z, acc); acc = __fmaf_rn(xb.w, wb.w, acc);
        acc = __fmaf_rn(xc.x, wc.x, acc); acc = __fmaf_rn(xc.y, wc.y, acc);
        acc = __fmaf_rn(xc.z, wc.z, acc); acc = __fmaf_rn(xc.w, wc.w, acc);
        acc = __fmaf_rn(xd.x, wd.x, acc); acc = __fmaf_rn(xd.y, wd.y, acc);
        acc = __fmaf_rn(xd.z, wd.z, acc); acc = __fmaf_rn(xd.w, wd.w, acc);
      }
      {
#pragma clang fp contract(off)
        const float sq = acc * acc;
        float rr[8];
#pragma unroll
        for (int j = 0; j < 8; ++j) rr[j] = __shfl(sq, j);
        for (int i = 8; i < 64; i += 8) {
#pragma unroll
          for (int j = 0; j < 8; ++j) rr[j] += __shfl(sq, i + j);
        }
        const float ss = ((rr[0] + rr[1]) + (rr[2] + rr[3])) +
                         ((rr[4] + rr[5]) + (rr[6] + rr[7]));
        const float nrm = __fsqrt_rn(ss);
        const float s = fminf(1.0f, 0.99999f / fmaxf(nrm, 1e-12f));
        const float c0 = __shfl(acc, 0) * s;
        const float c1 = __shfl(acc, 1) * s;
        const float cr = (float)atan2((double)c1, (double)c0);
        const float fd = fdlibm_atan2f(c1, c0);
        const float tol = fmaxf(fabsf(cr) * 6e-7f, 1e-30f);
        const float ang = (fabsf(fd - cr) <= tol) ? fd : cr;
        const float t = ((ang / 6.2831854820251465f) + 0.5f) * 512.0f;
        int b = (int)floorf(t);
        b = b < 0 ? 0 : (b > 511 ? 511 : b);
        if (d == 0) (isk ? kb : qb)[(h << 12) + n] = b;
      }
    }
    return;
  }

  // ---- GEMM path ----
  const int z = blk >> 7;
  const int rem = blk & 127;
  const int bm = (rem & 31) * 128;
  const int bn = (rem >> 5) * 128;

  const u16* A    = (z == 0) ? qx : (z == 1) ? kx : vx;
  const u16* W    = (z == 0) ? wqx : (z == 1) ? wkx : wvx;
  const float* bias = (z == 0) ? bq : (z == 1) ? bk : bv;
  u16* O          = (z == 0) ? Qb : (z == 1) ? Kb : Vb;

  const int lane = tid & 63;
  const int wave = tid >> 6;
  const int row4 = tid >> 2;
  const int seg  = tid & 3;
  const int wm = (wave & 1) * 64;
  const int wn = (wave >> 1) * 64;
  const int l15 = lane & 15;
  const int quad = lane >> 4;

  f32x4 acc[4][4] = {};

  for (int kt = 0; kt < DMODEL; kt += 32) {
    uint4 a0 = *(const uint4*)(A + (bm + row4) * DMODEL + kt + seg * 8);
    uint4 a1 = *(const uint4*)(A + (bm + row4 + 64) * DMODEL + kt + seg * 8);
    uint4 w0 = *(const uint4*)(W + (bn + row4) * DMODEL + kt + seg * 8);
    uint4 w1 = *(const uint4*)(W + (bn + row4 + 64) * DMODEL + kt + seg * 8);
    __syncthreads();
    *(uint4*)&As[row4 * 40 + seg * 8] = a0;
    *(uint4*)&As[(row4 + 64) * 40 + seg * 8] = a1;
    *(uint4*)&Ws[row4 * 40 + seg * 8] = w0;
    *(uint4*)&Ws[(row4 + 64) * 40 + seg * 8] = w1;
    __syncthreads();
    v8bf af[4], bfr[4];
#pragma unroll
    for (int i = 0; i < 4; ++i)
      af[i] = *(const v8bf*)&As[(wm + i * 16 + l15) * 40 + quad * 8];
#pragma unroll
    for (int j = 0; j < 4; ++j)
      bfr[j] = *(const v8bf*)&Ws[(wn + j * 16 + l15) * 40 + quad * 8];
#pragma unroll
    for (int i = 0; i < 4; ++i)
#pragma unroll
      for (int j = 0; j < 4; ++j)
        acc[i][j] = __builtin_amdgcn_mfma_f32_16x16x32_bf16(af[i], bfr[j], acc[i][j], 0, 0, 0);
  }

  float bval[4];
#pragma unroll
  for (int j = 0; j < 4; ++j) bval[j] = bias[bn + wn + j * 16 + l15];
  const int h = (bn + wn) >> 6;

#pragma unroll
  for (int i = 0; i < 4; ++i) {
#pragma unroll
    for (int r = 0; r < 4; ++r) {
      const int row = bm + wm + i * 16 + quad * 4 + r;
      float v0 = acc[i][0][r] + bval[0];
      float v1 = acc[i][1][r] + bval[1];
      float v2 = acc[i][2][r] + bval[2];
      float v3 = acc[i][3][r] + bval[3];
      if (z != 2) {
        float ss = v0 * v0 + v1 * v1 + v2 * v2 + v3 * v3;
#pragma unroll
        for (int o = 1; o < 16; o <<= 1) ss += __shfl_xor(ss, o);
        const float s = fminf(1.0f, MAX_NORM_F / fmaxf(sqrtf(ss), 1e-12f));
        v0 *= s; v1 *= s; v2 *= s; v3 *= s;
      }
      const int base = (((h << 12) + row) << 6) + l15;
      O[base +  0] = f2bf(v0); O[base + 16] = f2bf(v1);
      O[base + 32] = f2bf(v2); O[base + 48] = f2bf(v3);
    }
  }
}

// Histogram keys and queries into per-(h,bin) lists (UNORDERED — the
// rank-based selection downstream is order-invariant).
__global__ __launch_bounds__(256) void bin_hist_kernel(
    const int* __restrict__ kb, const int* __restrict__ qb,
    int* __restrict__ khist, u16* __restrict__ blist,
    int* __restrict__ qhist, u16* __restrict__ qlist)
{
  const int h = blockIdx.x;
  const int type = blockIdx.y;  // 0 = keys, 1 = queries
  const int* src = type ? qb : kb;
  int* hist = type ? qhist : khist;
  u16* list = type ? qlist : blist;
  const int cap = type ? QCAP : BINCAP;

  __shared__ int lhist[NBINS];
  for (int i = threadIdx.x; i < NBINS; i += 256) lhist[i] = 0;
  __syncthreads();
  for (int i = threadIdx.x; i < N_TOK; i += 256) {
    const int b = src[(h << 12) + i];
    const int pos = atomicAdd(&lhist[b], 1);
    if (pos < cap) list[((h << 9) + b) * cap + pos] = (u16)i;
  }
  __syncthreads();
  for (int i = threadIdx.x; i < NBINS; i += 256)
    hist[(h << 9) + i] = lhist[i] < cap ? lhist[i] : cap;
}

// ---------------------------------------------------------------------------
// Bin-batched MFMA attention with FUSED rank-based selection (one wave per
// (h,bin)): each element's rank in the 3-bin union = count of strictly
// smaller union elements; rank<CANDN -> s_cand[rank]. Bit-identical to the
// separate select kernel; saves a dispatch + the candb round-trip.
// ---------------------------------------------------------------------------
__global__ __launch_bounds__(64) void attn_bin_kernel(
    const u16* __restrict__ Qb, const u16* __restrict__ Kb,
    const u16* __restrict__ Vb, const int* __restrict__ qhist,
    const u16* __restrict__ qlist, const int* __restrict__ khist,
    const u16* __restrict__ blist, u16* __restrict__ aout)
{
  __shared__ u16 kf[4 * 2 * 4 * 16 * 8];
  __shared__ u16 vf[4 * 2 * 4 * 16 * 8];
  __shared__ u16 pf[16 * 72];
  __shared__ u16 s_cand[64];
  __shared__ int s_qg[16];

  const int hb = blockIdx.x;
  const int h = hb >> 9;
  const int b = hb & 511;
  const int qcnt = qhist[hb];
  if (qcnt == 0) return;

  const int lane = threadIdx.x;
  const int l15 = lane & 15;
  const int quad = lane >> 4;

  // ---- fused selection ----
  int v0 = 0xFFFF, v1 = 0xFFFF, v2 = 0xFFFF;
  int c0 = 0, c1 = 0, c2 = 0;
  if (b > 0) {
    c0 = khist[(h << 9) + b - 1];
    if (lane < c0) v0 = (int)blist[(((h << 9) + b - 1) << 6) + lane];
  }
  {
    c1 = khist[(h << 9) + b];
    if (lane < c1) v1 = (int)blist[(((h << 9) + b) << 6) + lane];
  }
  if (b < NBINS - 1) {
    c2 = khist[(h << 9) + b + 1];
    if (lane < c2) v2 = (int)blist[(((h << 9) + b + 1) << 6) + lane];
  }

  int r0 = 0, r1 = 0, r2 = 0;
#pragma unroll 8
  for (int j = 0; j < 64; ++j) {
    const int w0 = __shfl(v0, j);
    const int w1 = __shfl(v1, j);
    const int w2 = __shfl(v2, j);
    r0 += (w0 < v0) + (w1 < v0) + (w2 < v0);
    r1 += (w0 < v1) + (w1 < v1) + (w2 < v1);
    r2 += (w0 < v2) + (w1 < v2) + (w2 < v2);
  }
  const int tot = c0 + c1 + c2;
  const int ccnt = tot < CANDN ? tot : CANDN;
  const int ccnt_eff = (tot == 0) ? 64 : ccnt;
  if (tot == 0) {
    s_cand[lane] = (u16)lane;
  } else {
    if (v0 != 0xFFFF && r0 < CANDN) s_cand[r0] = (u16)v0;
    if (v1 != 0xFFFF && r1 < CANDN) s_cand[r1] = (u16)v1;
    if (v2 != 0xFFFF && r2 < CANDN) s_cand[r2] = (u16)v2;
  }
  __syncthreads();
  if (tot > 0 && lane >= ccnt) s_cand[lane] = s_cand[0];
  __syncthreads();

  // ---- K/V gathers into MFMA fragment order ----
  {
    const int r = lane >> 3, s = lane & 7;
    const int ks = s >> 2, qd = s & 3;
#pragma unroll
    for (int it = 0; it < 8; ++it) {
      const int key = it * 8 + r;
      const int c = s_cand[key];
      const uint4 kv = *(const uint4*)(Kb + ((h << 18) | (c << 6)) + s * 8);
      const int idx = ((((key >> 4) * 2 + ks) * 4 + qd) * 16 + (key & 15)) * 8;
      *(uint4*)&kf[idx] = kv;
    }
  }
  {
    const int r = lane >> 3, s = lane & 7;
    const int nt = s >> 1, d0 = (s & 1) * 8;
#pragma unroll
    for (int it = 0; it < 8; ++it) {
      const int key = it * 8 + r;
      const int c = s_cand[key];
      union { u16 hh[8]; uint4 u; } vv;
      vv.u = *(const uint4*)(Vb + ((h << 18) | (c << 6)) + s * 8);
      const int kstep = key >> 5, qd = (key >> 3) & 3, j = key & 7;
#pragma unroll
      for (int m = 0; m < 8; ++m)
        vf[(((nt * 2 + kstep) * 4 + qd) * 16 + d0 + m) * 8 + j] = vv.hh[m];
    }
  }
  __syncthreads();

  v8bf akf[4][2], bvf[4][2];
#pragma unroll
  for (int t = 0; t < 4; ++t)
#pragma unroll
    for (int ks = 0; ks < 2; ++ks) {
      akf[t][ks] = *(const v8bf*)&kf[(((t * 2 + ks) * 4 + quad) * 16 + l15) * 8];
      bvf[t][ks] = *(const v8bf*)&vf[(((t * 2 + ks) * 4 + quad) * 16 + l15) * 8];
    }

  const int nchunk = (qcnt + 15) >> 4;
  for (int ci = 0; ci < nchunk; ++ci) {
    const int base = ci << 4;
    const int qcn = min(16, qcnt - base);
    __syncthreads();
    if (lane < 16) {
      int idx = base + lane;
      if (idx > qcnt - 1) idx = qcnt - 1;
      s_qg[lane] = (int)qlist[(hb << 7) + idx];
    }
    __syncthreads();

    const u16* qrow = Qb + ((h << 18) | (s_qg[l15] << 6));
    v8bf bq[2];
#pragma unroll
    for (int ks = 0; ks < 2; ++ks)
      bq[ks] = *(const v8bf*)(qrow + ks * 32 + quad * 8);

    float sc[16];
#pragma unroll
    for (int t = 0; t < 4; ++t) {
      f32x4 sa = {0.f, 0.f, 0.f, 0.f};
      sa = __builtin_amdgcn_mfma_f32_16x16x32_bf16(akf[t][0], bq[0], sa, 0, 0, 0);
      sa = __builtin_amdgcn_mfma_f32_16x16x32_bf16(akf[t][1], bq[1], sa, 0, 0, 0);
#pragma unroll
      for (int r = 0; r < 4; ++r) {
        const int key = t * 16 + quad * 4 + r;
        sc[t * 4 + r] = (key < ccnt_eff) ? sa[r] * ATT_SCALE : -INFINITY;
      }
    }
    float mx = sc[0];
#pragma unroll
    for (int i = 1; i < 16; ++i) mx = fmaxf(mx, sc[i]);
    mx = fmaxf(mx, __shfl_xor(mx, 16));
    mx = fmaxf(mx, __shfl_xor(mx, 32));
    float sum = 0.0f;
    float pe[16];
#pragma unroll
    for (int i = 0; i < 16; ++i) { pe[i] = __expf(sc[i] - mx); sum += pe[i]; }
    sum += __shfl_xor(sum, 16);
    sum += __shfl_xor(sum, 32);
    const float inv = 1.0f / sum;

    __syncthreads();
#pragma unroll
    for (int t = 0; t < 4; ++t)
#pragma unroll
      for (int r = 0; r < 4; ++r)
        pf[l15 * 72 + t * 16 + quad * 4 + r] = f2bf(pe[t * 4 + r] * inv);
    __syncthreads();

    v8bf ap[2];
#pragma unroll
    for (int ks = 0; ks < 2; ++ks)
      ap[ks] = *(const v8bf*)&pf[l15 * 72 + ks * 32 + quad * 8];

#pragma unroll
    for (int nt = 0; nt < 4; ++nt) {
      f32x4 o = {0.f, 0.f, 0.f, 0.f};
      o = __builtin_amdgcn_mfma_f32_16x16x32_bf16(ap[0], bvf[nt][0], o, 0, 0, 0);
      o = __builtin_amdgcn_mfma_f32_16x16x32_bf16(ap[1], bvf[nt][1], o, 0, 0, 0);
#pragma unroll
      for (int r = 0; r < 4; ++r) {
        const int row = quad * 4 + r;
        if (row < qcn)
          aout[s_qg[row] * DMODEL + (h << 6) + nt * 16 + l15] = f2bf(o[r]);
      }
    }
  }
}

__global__ __launch_bounds__(256) void gemm_out_kernel(
    const u16* __restrict__ A, const u16* __restrict__ W,
    const float* __restrict__ bias, float* __restrict__ O)
{
  __shared__ u16 As[128 * 40];
  __shared__ u16 Ws[128 * 40];

  const int tid  = threadIdx.x;
  const int lane = tid & 63;
  const int wave = tid >> 6;
  const int row4 = tid >> 2;
  const int seg  = tid & 3;

  const int bm = blockIdx.x * 128;
  const int bn = blockIdx.y * 128;
  const int wm = (wave & 1) * 64;
  const int wn = (wave >> 1) * 64;
  const int l15 = lane & 15;
  const int quad = lane >> 4;

  f32x4 acc[4][4] = {};

  for (int kt = 0; kt < DMODEL; kt += 32) {
    uint4 a0 = *(const uint4*)(A + (bm + row4) * DMODEL + kt + seg * 8);
    uint4 a1 = *(const uint4*)(A + (bm + row4 + 64) * DMODEL + kt + seg * 8);
    uint4 w0 = *(const uint4*)(W + (bn + row4) * DMODEL + kt + seg * 8);
    uint4 w1 = *(const uint4*)(W + (bn + row4 + 64) * DMODEL + kt + seg * 8);
    __syncthreads();
    *(uint4*)&As[row4 * 40 + seg * 8] = a0;
    *(uint4*)&As[(row4 + 64) * 40 + seg * 8] = a1;
    *(uint4*)&Ws[row4 * 40 + seg * 8] = w0;
    *(uint4*)&Ws[(row4 + 64) * 40 + seg * 8] = w1;
    __syncthreads();
    v8bf af[4], bfr[4];
#pragma unroll
    for (int i = 0; i < 4; ++i)
      af[i] = *(const v8bf*)&As[(wm + i * 16 + l15) * 40 + quad * 8];
#pragma unroll
    for (int j = 0; j < 4; ++j)
      bfr[j] = *(const v8bf*)&Ws[(wn + j * 16 + l15) * 40 + quad * 8];
#pragma unroll
    for (int i = 0; i < 4; ++i)
#pragma unroll
      for (int j = 0; j < 4; ++j)
        acc[i][j] = __builtin_amdgcn_mfma_f32_16x16x32_bf16(af[i], bfr[j], acc[i][j], 0, 0, 0);
  }

#pragma unroll
  for (int j = 0; j < 4; ++j) {
    const int cg = bn + wn + j * 16 + l15;
    const float bval = bias[cg];
#pragma unroll
    for (int i = 0; i < 4; ++i) {
      const int rbase = bm + wm + i * 16 + quad * 4;
#pragma unroll
      for (int r = 0; r < 4; ++r)
        O[(rbase + r) * DMODEL + cg] = acc[i][j][r] + bval;
    }
  }
}

extern "C" void kernel_launch(void* const* d_in, const int* in_sizes, int n_in,
                              void* d_out, int out_size, void* d_ws, size_t ws_size,
                              hipStream_t stream) {
  const float* query = (const float*)d_in[0];
  const float* key_  = (const float*)d_in[1];
  const float* value = (const float*)d_in[2];
  const float* Wq = (const float*)d_in[3];
  const float* bq = (const float*)d_in[4];
  const float* Wk = (const float*)d_in[5];
  const float* bk = (const float*)d_in[6];
  const float* Wv = (const float*)d_in[7];
  const float* bv = (const float*)d_in[8];
  const float* Wo = (const float*)d_in[9];
  const float* bo = (const float*)d_in[10];

  char* ws = (char*)d_ws;
  u16* qx    = (u16*)(ws);                   // 4 MB
  u16* kx    = (u16*)(ws + 4194304);         // 4 MB
  u16* vx    = (u16*)(ws + 8388608);         // 4 MB
  u16* wqx   = (u16*)(ws + 12582912);        // 512 KB
  u16* wkx   = (u16*)(ws + 13107200);        // 512 KB
  u16* wvx   = (u16*)(ws + 13631488);        // 512 KB
  u16* wox   = (u16*)(ws + 14155776);        // 512 KB
  u16* Qb    = (u16*)(ws + 14680064);        // 4 MB [h][n][64] bf16 projected
  u16* Kb    = (u16*)(ws + 18874368);        // 4 MB
  u16* Vb    = (u16*)(ws + 23068672);        // 4 MB
  u16* aout  = (u16*)(ws + 27262976);        // 4 MB [n][512] bf16
  int* qb    = (int*)(ws + 31457280);        // 128 KB
  int* kb    = (int*)(ws + 31588352);        // 128 KB
  unsigned char* flags = (unsigned char*)(ws + 31719424);  // 64 KB
  int* khist = (int*)(ws + 31784960);        // 16 KB
  int* qhist = (int*)(ws + 31801344);        // 16 KB
  u16* blist = (u16*)(ws + 31817728);        // 512 KB [4096][64]
  u16* qlist = (u16*)(ws + 32342016);        // 1 MB  [4096][128]
  // total ~31.9 MB

  prep_kernel<<<4096, 256, 0, stream>>>(
      query, key_, value, Wq, Wk, Wv, Wo,
      qx, kx, vx, wqx, wkx, wvx, wox, qb, kb, flags);
  gemmfix_kernel<<<448, 256, 0, stream>>>(
      qx, kx, vx, wqx, wkx, wvx, bq, bk, bv,
      query, key_, Wq, Wk, flags, qb, kb, Qb, Kb, Vb);
  bin_hist_kernel<<<dim3(8, 2), 256, 0, stream>>>(
      kb, qb, khist, blist, qhist, qlist);
  attn_bin_kernel<<<4096, 64, 0, stream>>>(
      Qb, Kb, Vb, qhist, qlist, khist, blist, aout);
  gemm_out_kernel<<<dim3(32, 4), 256, 0, stream>>>(aout, wox, bo, (float*)d_out);
}